// Round 9
// baseline (209.163 us; speedup 1.0000x reference)
//
#include <hip/hip_runtime.h>
#include <hip/hip_bf16.h>
#include <cstdint>
#include <cstddef>

typedef __attribute__((ext_vector_type(4))) float f32x4;
typedef __attribute__((ext_vector_type(8))) short s16x8;
typedef __attribute__((ext_vector_type(8))) unsigned short u16x8;

#define NB 32
#define DD 512
#define TT 4096
#define HH 512
#define NKK 16    // K-steps of 32

__device__ __forceinline__ unsigned short f2bf(float f) {
  uint32_t u = __builtin_bit_cast(uint32_t, f);
  u += 0x7fffu + ((u >> 16) & 1u);   // RNE
  return (unsigned short)(u >> 16);
}

__device__ __forceinline__ uint32_t cvtpk(float a, float b) {
  uint32_t d;
  asm("v_cvt_pk_bf16_f32 %0, %1, %2" : "=v"(d) : "v"(a), "v"(b));
  return d;   // low16 = bf16(a), high16 = bf16(b)
}

__device__ __forceinline__ float tanh_fast(float x) {
  x = fminf(fmaxf(x, -15.f), 15.f);
  float e = __expf(2.f * x);
  return (e - 1.f) / (e + 1.f);
}

// --- A1: W1swz[kk32][s][h] : 16B chunk = W1[h][kk32*32+s*8 .. +7] bf16 ---
__global__ void kConvT(const float* __restrict__ w42, u16x8* __restrict__ W1swz) {
  int g = blockIdx.x * 256 + threadIdx.x;
  int h = g & 511, sk = g >> 9;
  int kk = sk >> 2, s = sk & 3;
  const float* src = &w42[h * 1024 + kk * 32 + s * 8];
  f32x4 v0 = *reinterpret_cast<const f32x4*>(src);
  f32x4 v1 = *reinterpret_cast<const f32x4*>(src + 4);
  u16x8 c;
  c[0] = f2bf(v0.x); c[1] = f2bf(v0.y); c[2] = f2bf(v0.z); c[3] = f2bf(v0.w);
  c[4] = f2bf(v1.x); c[5] = f2bf(v1.y); c[6] = f2bf(v1.z); c[7] = f2bf(v1.w);
  W1swz[kk * 2048 + s * 512 + h] = c;
}

// --- A2: qterm[b,h] = w42[h,512:]·query[b] + b4[h] ---
__global__ void kQterm(const float* __restrict__ w42, const float* __restrict__ query,
                       const float* __restrict__ b4, float* __restrict__ qterm) {
  int wid = blockIdx.x * 4 + (threadIdx.x >> 6);
  int lane = threadIdx.x & 63;
  int b = wid >> 9, h = wid & 511;
  const float* wr = &w42[h * 1024 + 512];
  const float* q  = &query[b * 512];
  int d = lane * 8;
  f32x4 w0 = *(const f32x4*)&wr[d], w1 = *(const f32x4*)&wr[d + 4];
  f32x4 q0 = *(const f32x4*)&q[d],  q1 = *(const f32x4*)&q[d + 4];
  float s = w0.x*q0.x + w0.y*q0.y + w0.z*q0.z + w0.w*q0.w
          + w1.x*q1.x + w1.y*q1.y + w1.z*q1.z + w1.w*q1.w;
  #pragma unroll
  for (int off = 32; off; off >>= 1) s += __shfl_xor(s, off);
  if (lane == 0) qterm[b * 512 + h] = s + b4[h];
}

// --- B: GEMM + tanh + partial h-reduce.
// Block 128h x 256t, 4 waves each 128h x 64t (acc[8][4]).
// A-slab (8 KB/step) cooperatively staged to LDS (reused by all waves);
// B loaded as coalesced f32x4 (1 KB/instr) -> cvtpk -> swizzled LDS chunks.
// Double-buffered LDS, ONE raw barrier per step, vmcnt never drained.
// hq-sibling blocks share keys via XCD-chunked grid mapping.
__global__ __launch_bounds__(256, 2) void kGemmE(
    const float* __restrict__ keys, const u16x8* __restrict__ W1swz,
    const float* __restrict__ qterm, const float* __restrict__ w54,
    float* __restrict__ n5p) {
  __shared__ s16x8 Asb[2 * 512];    // 16 KB: [buf][s*128 + h']
  __shared__ s16x8 Bsb[2 * 1024];   // 32 KB: [buf][s*256 + dt*64 + (u^(dt<<1)^s)]

  int p = blockIdx.x;
  int xcd = p & 7, local = p >> 3;       // bijective (2048 % 8 == 0)
  int hq = local & 3, g = local >> 2;    // g 0..63
  int pair = xcd * 64 + g;               // 4 hq-siblings of a pair -> same XCD
  int b = pair >> 4, tc = pair & 15;
  int tG = tc * 256;

  int tid = threadIdx.x, lane = tid & 63, w = tid >> 6;
  int lr = lane & 15, lg = lane >> 4;

  // B staging: wave w stages k-rows w*8..w*8+7 for all 256 t (lane u = t/4)
  int u = lane;
  const float* kpB = keys + (size_t)b * DD * TT + (size_t)(w * 8) * TT + tG + u * 4;
  // A staging: thread stages chunks c = tid, tid+256 of the 512-chunk slab
  const u16x8* apG0 = W1swz + (size_t)(tid >> 7) * 512 + hq * 128 + (tid & 127);
  const u16x8* apG1 = W1swz + (size_t)((tid + 256) >> 7) * 512 + hq * 128 + (tid & 127);

  // B LDS write chunk indices (4 per thread)
  int cW[4];
  #pragma unroll
  for (int dt = 0; dt < 4; ++dt) cW[dt] = w * 256 + dt * 64 + (u ^ (dt << 1) ^ w);
  // B LDS read chunk indices (wave reads its own 64-t slice, all k-slots)
  int rciB[4];
  #pragma unroll
  for (int n = 0; n < 4; ++n)
    rciB[n] = lg * 256 + (lr & 3) * 64 +
              ((w * 16 + n * 4 + (lr >> 2)) ^ ((lr & 3) << 1) ^ lg);

  f32x4 acc[8][4];
  #pragma unroll
  for (int m = 0; m < 8; ++m)
    #pragma unroll
    for (int n = 0; n < 4; ++n) acc[m][n] = (f32x4){0.f, 0.f, 0.f, 0.f};

  u16x8 ra0, ra1;
  f32x4 rb[8];
  // prologue: stage loads for step 0 (A first, then B; both needed together)
  ra0 = apG0[0]; ra1 = apG1[0];
  #pragma unroll
  for (int j = 0; j < 8; ++j)
    rb[j] = __builtin_nontemporal_load(reinterpret_cast<const f32x4*>(&kpB[(size_t)j * TT]));

  #pragma unroll
  for (int kk = 0; kk < NKK; ++kk) {
    const int cur = kk & 1;
    // ---- stage-write this step's slabs from regs ----
    *reinterpret_cast<u16x8*>(&Asb[(cur << 9) + tid])       = ra0;
    *reinterpret_cast<u16x8*>(&Asb[(cur << 9) + tid + 256]) = ra1;
    #pragma unroll
    for (int dt = 0; dt < 4; ++dt) {
      union { uint32_t q[4]; s16x8 v; } c;
      #pragma unroll
      for (int jj = 0; jj < 4; ++jj)
        c.q[jj] = cvtpk(rb[2 * jj][dt], rb[2 * jj + 1][dt]);
      Bsb[(cur << 10) + cW[dt]] = c.v;
    }
    // ---- issue next step's global loads (ride across the barrier) ----
    if (kk + 1 < NKK) {
      ra0 = apG0[(kk + 1) * 2048];
      ra1 = apG1[(kk + 1) * 2048];
      const float* kp2 = kpB + (size_t)(kk + 1) * 32 * TT;
      #pragma unroll
      for (int j = 0; j < 8; ++j)
        rb[j] = __builtin_nontemporal_load(reinterpret_cast<const f32x4*>(&kp2[(size_t)j * TT]));
    }
    asm volatile("s_waitcnt lgkmcnt(0)" ::: "memory");  // LDS writes visible
    __builtin_amdgcn_s_barrier();                        // vmcnt NOT drained

    // ---- fragments from LDS ----
    s16x8 af[8], bf[4];
    const s16x8* Ab = &Asb[cur << 9];
    #pragma unroll
    for (int m = 0; m < 8; ++m) af[m] = Ab[lg * 128 + m * 16 + lr];
    const s16x8* Bb = &Bsb[cur << 10];
    #pragma unroll
    for (int n = 0; n < 4; ++n) bf[n] = Bb[rciB[n]];

    #pragma unroll
    for (int m = 0; m < 8; ++m)
      #pragma unroll
      for (int n = 0; n < 4; ++n)
        acc[m][n] = __builtin_amdgcn_mfma_f32_16x16x32_bf16(af[m], bf[n], acc[m][n], 0, 0, 0);
  }

  // epilogue: tanh + w54-weighted reduce over this block's 128 h (per wave)
  float part[4] = {0.f, 0.f, 0.f, 0.f};
  #pragma unroll
  for (int m = 0; m < 8; ++m) {
    #pragma unroll
    for (int rr = 0; rr < 4; ++rr) {
      int h = hq * 128 + m * 16 + lg * 4 + rr;   // C/D: row=(lane>>4)*4+reg
      float qv = qterm[b * HH + h];
      float wv = w54[h];
      #pragma unroll
      for (int n = 0; n < 4; ++n)
        part[n] += wv * tanh_fast(acc[m][n][rr] + qv);
    }
  }
  #pragma unroll
  for (int n = 0; n < 4; ++n) {
    part[n] += __shfl_xor(part[n], 16);
    part[n] += __shfl_xor(part[n], 32);
  }
  if (lane < 16) {
    #pragma unroll
    for (int n = 0; n < 4; ++n)
      n5p[((size_t)hq * NB + b) * TT + tG + w * 64 + n * 16 + lane] = part[n];
  }
}

// --- C: e[b,t] = exp(sum_hq n5p);  Zinv[b] = 1/sum_t e ---
__global__ void kSoftE(const float* __restrict__ n5p, float* __restrict__ e,
                       float* __restrict__ Zinv) {
  int b = blockIdx.x, tid = threadIdx.x;
  int lane = tid & 63, wid = tid >> 6;
  __shared__ float zsh[4];
  float z = 0.f;
  #pragma unroll
  for (int i = 0; i < 16; ++i) {
    int t = tid + i * 256;
    float v = n5p[(0 * NB + b) * TT + t] + n5p[(1 * NB + b) * TT + t]
            + n5p[(2 * NB + b) * TT + t] + n5p[(3 * NB + b) * TT + t];
    float ev = __expf(v);                 // |n5| <~ 4: no max-sub needed
    e[b * TT + t] = ev;
    z += ev;
  }
  #pragma unroll
  for (int off = 32; off; off >>= 1) z += __shfl_xor(z, off);
  if (lane == 0) zsh[wid] = z;
  __syncthreads();
  if (tid == 0) Zinv[b] = 1.f / (zsh[0] + zsh[1] + zsh[2] + zsh[3]);
}

// --- D: out[b,v] = Zinv[b] * values[b,v,:]·e[b,:] ---
__global__ void kOut(const float* __restrict__ values, const float* __restrict__ e,
                     const float* __restrict__ Zinv, float* __restrict__ out) {
  int blk = blockIdx.x;
  int b = blk >> 7;
  int wid = threadIdx.x >> 6, lane = threadIdx.x & 63;
  int v = (blk & 127) * 4 + wid;
  const float* row = &values[((size_t)b * 512 + v) * TT];
  const float* wv = &e[b * TT];
  float s0 = 0.f, s1 = 0.f, s2 = 0.f, s3 = 0.f;
  #pragma unroll
  for (int i = 0; i < 16; ++i) {
    int t = (i * 64 + lane) * 4;
    f32x4 x = __builtin_nontemporal_load(reinterpret_cast<const f32x4*>(&row[t]));
    f32x4 y = *(const f32x4*)&wv[t];
    float d = x.x * y.x + x.y * y.y + x.z * y.z + x.w * y.w;
    if ((i & 3) == 0) s0 += d; else if ((i & 3) == 1) s1 += d;
    else if ((i & 3) == 2) s2 += d; else s3 += d;
  }
  float s = (s0 + s1) + (s2 + s3);
  #pragma unroll
  for (int off = 32; off; off >>= 1) s += __shfl_xor(s, off);
  if (lane == 0) out[b * 512 + v] = s * Zinv[b];
}

extern "C" void kernel_launch(void* const* d_in, const int* in_sizes, int n_in,
                              void* d_out, int out_size, void* d_ws, size_t ws_size,
                              hipStream_t stream) {
  const float* query  = (const float*)d_in[0];
  const float* keys   = (const float*)d_in[1];
  const float* values = (const float*)d_in[2];
  const float* w42    = (const float*)d_in[3];
  const float* b4     = (const float*)d_in[4];
  const float* w54    = (const float*)d_in[5];
  // d_in[6] (b5) shifts n5 by a constant -> softmax-invariant; unused.
  float* out = (float*)d_out;

  char* ws = (char*)d_ws;
  u16x8* W1swz = (u16x8*)ws;                       // 512 KB
  float* qterm = (float*)(ws + (512 << 10));       // 64 KB
  float* Zinv  = (float*)(ws + (576 << 10));       // 128 B
  float* e     = (float*)(ws + (640 << 10));       // 512 KB [B][T]
  float* n5p   = (float*)(ws + (1152 << 10));      // 2 MB   [4][B][T]

  kConvT <<<128, 256, 0, stream>>>(w42, W1swz);
  kQterm <<<4096, 256, 0, stream>>>(w42, query, b4, qterm);
  kGemmE <<<2048, 256, 0, stream>>>(keys, W1swz, qterm, w54, n5p);
  kSoftE <<<32, 256, 0, stream>>>(n5p, e, Zinv);
  kOut   <<<4096, 256, 0, stream>>>(values, e, Zinv, out);
}

// Round 10
// 183.676 us; speedup vs baseline: 1.1388x; 1.1388x over previous
//
#include <hip/hip_runtime.h>
#include <hip/hip_bf16.h>
#include <cstdint>
#include <cstddef>

typedef __attribute__((ext_vector_type(4))) float f32x4;
typedef __attribute__((ext_vector_type(8))) short s16x8;
typedef __attribute__((ext_vector_type(8))) unsigned short u16x8;

#define NB 32
#define DD 512
#define TT 4096
#define HH 512
#define NKK 16    // K-steps of 32

__device__ __forceinline__ unsigned short f2bf(float f) {
  uint32_t u = __builtin_bit_cast(uint32_t, f);
  u += 0x7fffu + ((u >> 16) & 1u);   // RNE
  return (unsigned short)(u >> 16);
}

__device__ __forceinline__ uint32_t cvtpk(float a, float b) {
  uint32_t d;
  asm("v_cvt_pk_bf16_f32 %0, %1, %2" : "=v"(d) : "v"(a), "v"(b));
  return d;   // low16 = bf16(a), high16 = bf16(b)
}

__device__ __forceinline__ float tanh_fast(float x) {
  x = fminf(fmaxf(x, -15.f), 15.f);
  float e = __expf(2.f * x);
  return (e - 1.f) / (e + 1.f);
}

// --- A1: W1swz[kk32][s][h] : 16B chunk = W1[h][kk32*32+s*8 .. +7] bf16 ---
__global__ void kConvT(const float* __restrict__ w42, u16x8* __restrict__ W1swz) {
  int g = blockIdx.x * 256 + threadIdx.x;
  int h = g & 511, sk = g >> 9;
  int kk = sk >> 2, s = sk & 3;
  const float* src = &w42[h * 1024 + kk * 32 + s * 8];
  f32x4 v0 = *reinterpret_cast<const f32x4*>(src);
  f32x4 v1 = *reinterpret_cast<const f32x4*>(src + 4);
  u16x8 c;
  c[0] = f2bf(v0.x); c[1] = f2bf(v0.y); c[2] = f2bf(v0.z); c[3] = f2bf(v0.w);
  c[4] = f2bf(v1.x); c[5] = f2bf(v1.y); c[6] = f2bf(v1.z); c[7] = f2bf(v1.w);
  W1swz[kk * 2048 + s * 512 + h] = c;
}

// --- A2: qterm[b,h] = w42[h,512:]·query[b] + b4[h] ---
__global__ void kQterm(const float* __restrict__ w42, const float* __restrict__ query,
                       const float* __restrict__ b4, float* __restrict__ qterm) {
  int wid = blockIdx.x * 4 + (threadIdx.x >> 6);
  int lane = threadIdx.x & 63;
  int b = wid >> 9, h = wid & 511;
  const float* wr = &w42[h * 1024 + 512];
  const float* q  = &query[b * 512];
  int d = lane * 8;
  f32x4 w0 = *(const f32x4*)&wr[d], w1 = *(const f32x4*)&wr[d + 4];
  f32x4 q0 = *(const f32x4*)&q[d],  q1 = *(const f32x4*)&q[d + 4];
  float s = w0.x*q0.x + w0.y*q0.y + w0.z*q0.z + w0.w*q0.w
          + w1.x*q1.x + w1.y*q1.y + w1.z*q1.z + w1.w*q1.w;
  #pragma unroll
  for (int off = 32; off; off >>= 1) s += __shfl_xor(s, off);
  if (lane == 0) qterm[b * 512 + h] = s + b4[h];
}

// --- B: GEMM + tanh + h-reduce + exp.  Block 512h x 64t, 4 waves (128h each).
// TA-minimal: B = 2x f32x4/thread (1KB/instr), A = dwordx4 chunks from L2.
// Depth-2 B pipeline, issue-before-write, raw barrier, vmcnt never drained.
// LDS chunk = (k-pair p, t-quad tg), slot = p*16+(tg^p): reads 2-way max.
__global__ __launch_bounds__(256, 2) void kGemmE(
    const float* __restrict__ keys, const u16x8* __restrict__ W1swz,
    const float* __restrict__ qterm, const float* __restrict__ w54,
    float* __restrict__ e, float* __restrict__ Zp) {
  __shared__ s16x8 Bs[2][256];   // 8 KB: [buf][slot p*16+(tg^p)]
  __shared__ float red[4][64];

  int bid = blockIdx.x;
  int b = bid >> 6, tblk = bid & 63;
  int t0 = tblk * 64;
  int tid = threadIdx.x, lane = tid & 63, w = tid >> 6;
  int lr = lane & 15, lg = lane >> 4;

  // B staging: thread = (k-pair p, t-quad tg); rows 2p,2p+1; t = t0+tg*4..+3
  int p = tid >> 4, tg = tid & 15;
  const float* kp0 = keys + (size_t)b * DD * TT + (size_t)(2 * p) * TT + t0 + tg * 4;
  const float* kp1 = kp0 + TT;
  int wsl = p * 16 + (tg ^ p);
  // A-frags: chunk (kk, slot lg, h = w*128 + m*16 + lr)
  const s16x8* ap = reinterpret_cast<const s16x8*>(W1swz) + lg * 512 + w * 128 + lr;
  // B-frag read bases: dword idx = base2[pp] ^ (n*16)
  int base2[4];
  #pragma unroll
  for (int pp = 0; pp < 4; ++pp) {
    int pq = lg * 4 + pp;
    int q0 = lr >> 2;
    base2[pp] = (pq * 64 + (q0 ^ (pq & 3)) * 4 + (lr & 3)) ^ (lg << 4);
  }

  f32x4 acc[8][4];
  #pragma unroll
  for (int m = 0; m < 8; ++m)
    #pragma unroll
    for (int n = 0; n < 4; ++n) acc[m][n] = (f32x4){0.f, 0.f, 0.f, 0.f};

  s16x8 af[2][8];
  f32x4 rb[2][2];
  // prologue: A(0), B(0), A(1), B(1)
  #pragma unroll
  for (int m = 0; m < 8; ++m) af[0][m] = ap[m * 16];
  rb[0][0] = __builtin_nontemporal_load(reinterpret_cast<const f32x4*>(kp0));
  rb[0][1] = __builtin_nontemporal_load(reinterpret_cast<const f32x4*>(kp1));
  #pragma unroll
  for (int m = 0; m < 8; ++m) af[1][m] = ap[2048 + m * 16];
  rb[1][0] = __builtin_nontemporal_load(reinterpret_cast<const f32x4*>(kp0 + (size_t)32 * TT));
  rb[1][1] = __builtin_nontemporal_load(reinterpret_cast<const f32x4*>(kp1 + (size_t)32 * TT));

  #pragma unroll
  for (int kk = 0; kk < NKK; ++kk) {
    const int cur = kk & 1;
    // stage-write B(kk): 4 cvtpk -> one b128 (compiler waits vmcnt(10))
    union { uint32_t q[4]; s16x8 v; } c;
    #pragma unroll
    for (int dt = 0; dt < 4; ++dt) c.q[dt] = cvtpk(rb[cur][0][dt], rb[cur][1][dt]);
    Bs[cur][wsl] = c.v;
    // issue B(kk+2) (depth-2; rides across barriers)
    if (kk + 2 < NKK) {
      rb[cur][0] = __builtin_nontemporal_load(
          reinterpret_cast<const f32x4*>(kp0 + (size_t)(kk + 2) * 32 * TT));
      rb[cur][1] = __builtin_nontemporal_load(
          reinterpret_cast<const f32x4*>(kp1 + (size_t)(kk + 2) * 32 * TT));
    }
    asm volatile("s_waitcnt lgkmcnt(0)" ::: "memory");
    __builtin_amdgcn_s_barrier();          // vmcnt NOT drained

    // B fragments: 16 ds_read_b32, 2-way max bank aliasing
    const uint32_t* B32 = reinterpret_cast<const uint32_t*>(&Bs[cur][0]);
    s16x8 bf[4];
    #pragma unroll
    for (int n = 0; n < 4; ++n) {
      union { uint32_t q[4]; s16x8 v; } bb;
      #pragma unroll
      for (int pp = 0; pp < 4; ++pp) bb.q[pp] = B32[base2[pp] ^ (n * 16)];
      bf[n] = bb.v;
    }
    #pragma unroll
    for (int m = 0; m < 8; ++m)
      #pragma unroll
      for (int n = 0; n < 4; ++n)
        acc[m][n] = __builtin_amdgcn_mfma_f32_16x16x32_bf16(af[cur][m], bf[n], acc[m][n], 0, 0, 0);
    // issue A(kk+2) after MFMAs consumed af[cur]
    if (kk + 2 < NKK) {
      #pragma unroll
      for (int m = 0; m < 8; ++m) af[cur][m] = ap[(kk + 2) * 2048 + m * 16];
    }
  }

  // epilogue: tanh + w54-weighted reduce over this wave's 128 h
  float part[4] = {0.f, 0.f, 0.f, 0.f};
  int hb = w * 128;
  #pragma unroll
  for (int m = 0; m < 8; ++m) {
    #pragma unroll
    for (int rr = 0; rr < 4; ++rr) {
      int h = hb + m * 16 + lg * 4 + rr;     // C/D: row=(lane>>4)*4+reg
      float qv = qterm[b * HH + h];
      float wv = w54[h];
      #pragma unroll
      for (int n = 0; n < 4; ++n)
        part[n] += wv * tanh_fast(acc[m][n][rr] + qv);
    }
  }
  #pragma unroll
  for (int n = 0; n < 4; ++n) {
    part[n] += __shfl_xor(part[n], 16);
    part[n] += __shfl_xor(part[n], 32);
  }
  if (lane < 16) {
    #pragma unroll
    for (int n = 0; n < 4; ++n) red[w][n * 16 + lane] = part[n];
  }
  __syncthreads();
  if (tid < 64) {
    float v = red[0][tid] + red[1][tid] + red[2][tid] + red[3][tid];
    float ev = __expf(v);                    // |n5| <~ 4: no max-sub needed
    e[b * TT + t0 + tid] = ev;
    float z = ev;
    #pragma unroll
    for (int off = 32; off; off >>= 1) z += __shfl_xor(z, off);
    if (tid == 0) Zp[b * 64 + tblk] = z;
  }
}

// --- C: Zinv[b] = 1 / sum_tiles Zp[b][tile] ---
__global__ void kZinv(const float* __restrict__ Zp, float* __restrict__ Zinv) {
  int b = blockIdx.x, lane = threadIdx.x;
  float z = Zp[b * 64 + lane];
  #pragma unroll
  for (int off = 32; off; off >>= 1) z += __shfl_xor(z, off);
  if (lane == 0) Zinv[b] = 1.f / z;
}

// --- D: out[b,v] = Zinv[b] * values[b,v,:]·e[b,:] ---
__global__ void kOut(const float* __restrict__ values, const float* __restrict__ e,
                     const float* __restrict__ Zinv, float* __restrict__ out) {
  int blk = blockIdx.x;
  int b = blk >> 7;
  int wid = threadIdx.x >> 6, lane = threadIdx.x & 63;
  int v = (blk & 127) * 4 + wid;
  const float* row = &values[((size_t)b * 512 + v) * TT];
  const float* wv = &e[b * TT];
  float s0 = 0.f, s1 = 0.f, s2 = 0.f, s3 = 0.f;
  #pragma unroll
  for (int i = 0; i < 16; ++i) {
    int t = (i * 64 + lane) * 4;
    f32x4 x = __builtin_nontemporal_load(reinterpret_cast<const f32x4*>(&row[t]));
    f32x4 y = *(const f32x4*)&wv[t];
    float d = x.x * y.x + x.y * y.y + x.z * y.z + x.w * y.w;
    if ((i & 3) == 0) s0 += d; else if ((i & 3) == 1) s1 += d;
    else if ((i & 3) == 2) s2 += d; else s3 += d;
  }
  float s = (s0 + s1) + (s2 + s3);
  #pragma unroll
  for (int off = 32; off; off >>= 1) s += __shfl_xor(s, off);
  if (lane == 0) out[b * 512 + v] = s * Zinv[b];
}

extern "C" void kernel_launch(void* const* d_in, const int* in_sizes, int n_in,
                              void* d_out, int out_size, void* d_ws, size_t ws_size,
                              hipStream_t stream) {
  const float* query  = (const float*)d_in[0];
  const float* keys   = (const float*)d_in[1];
  const float* values = (const float*)d_in[2];
  const float* w42    = (const float*)d_in[3];
  const float* b4     = (const float*)d_in[4];
  const float* w54    = (const float*)d_in[5];
  // d_in[6] (b5) shifts n5 by a constant -> softmax-invariant; unused.
  float* out = (float*)d_out;

  char* ws = (char*)d_ws;
  u16x8* W1swz = (u16x8*)ws;                       // 512 KB
  float* qterm = (float*)(ws + (512 << 10));       // 64 KB
  float* Zp    = (float*)(ws + (576 << 10));       // 8 KB  [B][64]
  float* Zinv  = (float*)(ws + (592 << 10));       // 128 B
  float* e     = (float*)(ws + (640 << 10));       // 512 KB [B][T]

  kConvT <<<128, 256, 0, stream>>>(w42, W1swz);
  kQterm <<<4096, 256, 0, stream>>>(w42, query, b4, qterm);
  kGemmE <<<2048, 256, 0, stream>>>(keys, W1swz, qterm, w54, e, Zp);
  kZinv  <<<32, 64, 0, stream>>>(Zp, Zinv);
  kOut   <<<4096, 256, 0, stream>>>(values, e, Zinv, out);
}